// Round 7
// baseline (3197.781 us; speedup 1.0000x reference)
//
#include <hip/hip_runtime.h>

#define NB 64
#define TT 512
#define DD 1024
#define HH 1024

typedef unsigned long long u64;
typedef __attribute__((ext_vector_type(4))) float f32x4;
typedef __attribute__((ext_vector_type(8))) short bf16x8;

static __device__ __forceinline__ unsigned short f2bf(float f) {
  unsigned u = __float_as_uint(f);
  unsigned r = (u + 0x7fffu + ((u >> 16) & 1u)) >> 16;
  return (unsigned short)r;
}
static __device__ __forceinline__ float bf2f(unsigned short u) {
  return __uint_as_float(((unsigned)u) << 16);
}
// tanh(x) = 1 - 2/(e^{2x}+1), branch-free, saturating, ~1e-6 rel err
static __device__ __forceinline__ float ftanh(float x) {
  float z = __builtin_amdgcn_exp2f(x * 2.8853900817779268f);
  return 1.f - 2.f * __builtin_amdgcn_rcpf(z + 1.f);
}
static __device__ __forceinline__ void async_copy16(void* lds, const void* g) {
  __builtin_amdgcn_global_load_lds(
      (const __attribute__((address_space(1))) unsigned int*)g,
      (__attribute__((address_space(3))) unsigned int*)lds, 16, 0, 0);
}

// ---------------------------------------------------------------- prep -----
// blocks [0,nx): x fp32 -> xbf bf16, XOR-permuted global layout
// blocks [nx, nx+1024): transpose+split Wx -> Wxh/Wxl (permuted iff fast)
// blocks [nx+1024, nx+1152): h0 -> tagged packets (tag 0) in hbuf buffer 0
__global__ __launch_bounds__(256) void prep_kernel(
    const float* __restrict__ x, const float* __restrict__ Wx,
    const float* __restrict__ h0, unsigned short* __restrict__ Wxh,
    unsigned short* __restrict__ Wxl, u64* __restrict__ hbuf,
    unsigned short* __restrict__ xbf, int nx, int permuted) {
  __shared__ float tile[32][33];
  int b = blockIdx.x;
  int tid = threadIdx.x;
  if (b < nx) {
    int g = b * 256 + tid;
    int r = g >> 7, jb = g & 127;
    int q = jb >> 3, j = jb & 7;
    const float4* src = (const float4*)(x + r * 1024 + jb * 8);
    float4 a0 = src[0], a1 = src[1];
    uint4 o;
    o.x = (unsigned)f2bf(a0.x) | ((unsigned)f2bf(a0.y) << 16);
    o.y = (unsigned)f2bf(a0.z) | ((unsigned)f2bf(a0.w) << 16);
    o.z = (unsigned)f2bf(a1.x) | ((unsigned)f2bf(a1.y) << 16);
    o.w = (unsigned)f2bf(a1.z) | ((unsigned)f2bf(a1.w) << 16);
    *(uint4*)((char*)xbf + (size_t)r * 2048 + q * 128 + ((j ^ (r & 7)) << 4)) = o;
  } else if (b < nx + 1024) {
    int bb = b - nx;
    int tk = (bb & 31) * 32;
    int tn = (bb >> 5) * 32;
    int tx = tid & 31;
    int ty = tid >> 5;
#pragma unroll
    for (int ii = 0; ii < 4; ++ii) {
      int kk = ty + ii * 8;
      tile[kk][tx] = Wx[(tk + kk) * HH + tn + tx];
    }
    __syncthreads();
#pragma unroll
    for (int ii = 0; ii < 4; ++ii) {
      int a = ty + ii * 8;
      float wv = tile[tx][a];
      unsigned short hi = f2bf(wv);
      float lo = wv - bf2f(hi);
      int c = tn + a, k = tk + tx;
      int idx;
      if (permuted) {
        int qq = k >> 6, e = k & 63, j = e >> 3;
        idx = c * 1024 + qq * 64 + ((j ^ (c & 7)) << 3) + (e & 7);
      } else {
        idx = c * 1024 + k;
      }
      Wxh[idx] = hi;
      Wxl[idx] = f2bf(lo);
    }
  } else {
    // packet pi: row n = pi>>9 (0..63), colpair c2 = pi&511; tag 0 in hi32
    int pi = (b - nx - 1024) * 256 + tid;  // 0..32767
    int n = pi >> 9, c2 = pi & 511;
    float v0 = h0[n * HH + c2 * 2];
    float v1 = h0[n * HH + c2 * 2 + 1];
    unsigned lo32 = (unsigned)f2bf(v0) | ((unsigned)f2bf(v1) << 16);
    __hip_atomic_store(hbuf + pi, (u64)lo32, __ATOMIC_RELAXED,
                       __HIP_MEMORY_SCOPE_AGENT);
  }
}

// -------------------------------------------------------- xw GEMM (fast) ---
__global__ __launch_bounds__(256) void xw_gemm_fast(
    const unsigned short* __restrict__ xbf,
    const unsigned short* __restrict__ Wxh,
    const unsigned short* __restrict__ Wxl, const float* __restrict__ bias,
    float* __restrict__ out) {
  __shared__ unsigned short As[128 * 64];
  __shared__ unsigned short Bh[128 * 64];
  __shared__ unsigned short Bl[128 * 64];
  int tid = threadIdx.x;
  int w = tid >> 6, lane = tid & 63;
  int n0 = blockIdx.x * 128, row0 = blockIdx.y * 128;
  int wr = w >> 1, wc = w & 1;

  f32x4 acc[4][4];
#pragma unroll
  for (int m = 0; m < 4; ++m)
#pragma unroll
    for (int n = 0; n < 4; ++n) acc[m][n] = (f32x4)0.f;

  const char* xb = (const char*)xbf;
  const char* hb = (const char*)Wxh;
  const char* lb = (const char*)Wxl;

  for (int kc = 0; kc < 16; ++kc) {
    __syncthreads();
#pragma unroll
    for (int i = 0; i < 4; ++i) {
      int ub = i * 4096 + w * 1024;
      int off = ub + lane * 16;
      int r = off >> 7, inrow = off & 127;
      async_copy16((char*)As + ub,
                   xb + (size_t)(row0 + r) * 2048 + kc * 128 + inrow);
    }
#pragma unroll
    for (int i = 0; i < 4; ++i) {
      int ub = i * 4096 + w * 1024;
      int off = ub + lane * 16;
      int c = off >> 7, inrow = off & 127;
      async_copy16((char*)Bh + ub,
                   hb + (size_t)(n0 + c) * 2048 + kc * 128 + inrow);
      async_copy16((char*)Bl + ub,
                   lb + (size_t)(n0 + c) * 2048 + kc * 128 + inrow);
    }
    asm volatile("s_waitcnt vmcnt(0)" ::: "memory");
    __syncthreads();
#pragma unroll
    for (int kt = 0; kt < 2; ++kt) {
      int krel2 = (kt * 32 + ((lane >> 4) << 3)) * 2;
      bf16x8 af[4], bhf[4], blf[4];
#pragma unroll
      for (int m = 0; m < 4; ++m) {
        int r = wr * 64 + m * 16 + (lane & 15);
        af[m] = *(const bf16x8*)((const char*)As + r * 128 +
                                 (krel2 ^ ((r & 7) << 4)));
      }
#pragma unroll
      for (int n = 0; n < 4; ++n) {
        int c = wc * 64 + n * 16 + (lane & 15);
        int off = c * 128 + (krel2 ^ ((c & 7) << 4));
        bhf[n] = *(const bf16x8*)((const char*)Bh + off);
        blf[n] = *(const bf16x8*)((const char*)Bl + off);
      }
#pragma unroll
      for (int m = 0; m < 4; ++m)
#pragma unroll
        for (int n = 0; n < 4; ++n) {
          acc[m][n] = __builtin_amdgcn_mfma_f32_16x16x32_bf16(af[m], bhf[n],
                                                              acc[m][n], 0, 0, 0);
          acc[m][n] = __builtin_amdgcn_mfma_f32_16x16x32_bf16(af[m], blf[n],
                                                              acc[m][n], 0, 0, 0);
        }
    }
  }

#pragma unroll
  for (int n = 0; n < 4; ++n) {
    int col = n0 + wc * 64 + n * 16 + (lane & 15);
    float bv = bias[col];
#pragma unroll
    for (int m = 0; m < 4; ++m) {
      int rbase = row0 + wr * 64 + m * 16 + ((lane >> 4) << 2);
#pragma unroll
      for (int i = 0; i < 4; ++i)
        out[(size_t)(rbase + i) * HH + col] = acc[m][n][i] + bv;
    }
  }
}

// -------------------------------------------------------- xw GEMM (slow) ---
__global__ __launch_bounds__(256) void xw_gemm_slow(
    const float* __restrict__ x, const unsigned short* __restrict__ Wxh,
    const unsigned short* __restrict__ Wxl, const float* __restrict__ bias,
    float* __restrict__ out) {
  __shared__ unsigned short As[128 * 64];
  __shared__ unsigned short Bh[128 * 64];
  __shared__ unsigned short Bl[128 * 64];

  int tid = threadIdx.x;
  int n0 = blockIdx.x * 128;
  int row0 = blockIdx.y * 128;
  int w = tid >> 6, lane = tid & 63;
  int wr = w >> 1, wc = w & 1;

  f32x4 acc[4][4];
#pragma unroll
  for (int m = 0; m < 4; ++m)
#pragma unroll
    for (int n = 0; n < 4; ++n) acc[m][n] = (f32x4)0.f;

  for (int kk = 0; kk < DD; kk += 64) {
    float4 av[8];
#pragma unroll
    for (int i = 0; i < 8; ++i) {
      int lin = tid + 256 * i;
      int r = lin >> 4, kq = lin & 15;
      av[i] = *(const float4*)(x + (size_t)(row0 + r) * DD + kk + kq * 4);
    }
    int4 bhv[4], blv[4];
#pragma unroll
    for (int i = 0; i < 4; ++i) {
      int lin = tid + 256 * i;
      int c = lin >> 3, kb = lin & 7;
      bhv[i] = *(const int4*)(Wxh + (size_t)(n0 + c) * DD + kk + kb * 8);
      blv[i] = *(const int4*)(Wxl + (size_t)(n0 + c) * DD + kk + kb * 8);
    }
    __syncthreads();
#pragma unroll
    for (int i = 0; i < 8; ++i) {
      int lin = tid + 256 * i;
      int r = lin >> 4, kq = lin & 15;
      uint2 u;
      u.x = (unsigned)f2bf(av[i].x) | ((unsigned)f2bf(av[i].y) << 16);
      u.y = (unsigned)f2bf(av[i].z) | ((unsigned)f2bf(av[i].w) << 16);
      *(uint2*)((char*)As + r * 128 + ((kq * 8) ^ ((r & 7) << 4))) = u;
    }
#pragma unroll
    for (int i = 0; i < 4; ++i) {
      int lin = tid + 256 * i;
      int c = lin >> 3, kb = lin & 7;
      int off = c * 128 + ((kb * 16) ^ ((c & 7) << 4));
      *(int4*)((char*)Bh + off) = bhv[i];
      *(int4*)((char*)Bl + off) = blv[i];
    }
    __syncthreads();
#pragma unroll
    for (int kt = 0; kt < 2; ++kt) {
      int krel2 = (kt * 32 + ((lane >> 4) << 3)) * 2;
      bf16x8 af[4], bhf[4], blf[4];
#pragma unroll
      for (int m = 0; m < 4; ++m) {
        int r = wr * 64 + m * 16 + (lane & 15);
        af[m] = *(const bf16x8*)((const char*)As + r * 128 +
                                 (krel2 ^ ((r & 7) << 4)));
      }
#pragma unroll
      for (int n = 0; n < 4; ++n) {
        int c = wc * 64 + n * 16 + (lane & 15);
        int off = c * 128 + (krel2 ^ ((c & 7) << 4));
        bhf[n] = *(const bf16x8*)((const char*)Bh + off);
        blf[n] = *(const bf16x8*)((const char*)Bl + off);
      }
#pragma unroll
      for (int m = 0; m < 4; ++m)
#pragma unroll
        for (int n = 0; n < 4; ++n) {
          acc[m][n] = __builtin_amdgcn_mfma_f32_16x16x32_bf16(af[m], bhf[n],
                                                              acc[m][n], 0, 0, 0);
          acc[m][n] = __builtin_amdgcn_mfma_f32_16x16x32_bf16(af[m], blf[n],
                                                              acc[m][n], 0, 0, 0);
        }
    }
    __syncthreads();
  }

#pragma unroll
  for (int n = 0; n < 4; ++n) {
    int col = n0 + wc * 64 + n * 16 + (lane & 15);
    float bv = bias[col];
#pragma unroll
    for (int m = 0; m < 4; ++m) {
      int rbase = row0 + wr * 64 + m * 16 + ((lane >> 4) << 2);
#pragma unroll
      for (int i = 0; i < 4; ++i)
        out[(size_t)(rbase + i) * HH + col] = acc[m][n][i] + bv;
    }
  }
}

// ---------------------------------------------------------------- scan -----
// 4 groups x 16 rows; 16 WGs x 64 cols per group; Wh hi/lo in registers.
// h exchange: 8B tagged packets [tag:u32 | 2 bf16], agent-scope (LLC),
// 4-buffer rotation. WHOLE-BATCH retry: issue all 32 loads, drain once,
// check all tags, retry the full batch (1 RTT per round) — unlike r3's
// per-kt serial retry chains. Producer is fire-and-forget: tanh -> 2 tagged
// stores -> next step. No flags, no store-ack wait, no step-end barrier.
// Safety: WG at step t has consumed ALL of its group's step t-1 => skew<=1
// => 4 buffers race-free. hbuf memset each launch => no stale-tag aliasing.
__global__ __launch_bounds__(256) void rnn_scan(
    const float* __restrict__ Wh, float* __restrict__ out,
    u64* __restrict__ hbuf) {
  int tid = threadIdx.x;
  int w = tid >> 6, lane = tid & 63;
  int p = blockIdx.x >> 4;  // batch group 0..3
  int q = blockIdx.x & 15;  // col group 0..15
  int n0 = p * 16;
  int c0 = q * 64;

  __shared__ float red[2][4][16][68];

  // ---- Wh hi/lo fragments resident in registers, MFMA B-layout ----
  bf16x8 whi[4][8], wlo[4][8];
#pragma unroll
  for (int ct = 0; ct < 4; ++ct) {
#pragma unroll
    for (int kt = 0; kt < 8; ++kt) {
      int c = c0 + ct * 16 + (lane & 15);
      int kb = w * 256 + kt * 32 + ((lane >> 4) << 3);
#pragma unroll
      for (int j = 0; j < 8; ++j) {
        float wf = Wh[(size_t)(kb + j) * HH + c];
        unsigned short hi = f2bf(wf);
        whi[ct][kt][j] = (short)hi;
        wlo[ct][kt][j] = (short)f2bf(wf - bf2f(hi));
      }
    }
  }

  int erow_l = tid >> 4;  // 0..15
  int erow = n0 + erow_l;
  int ecol = c0 + ((tid & 15) << 2);
  size_t obase = (size_t)erow * (TT * HH) + ecol;
  int pstore = (p * 16 + erow_l) * 512 + (ecol >> 1);  // 2 packets here
  // consumer packet base: row = lane&15, colpair = w*128 + kt*16 + (lane>>4)*4
  int pload = (p * 16 + (lane & 15)) * 512 + w * 128 + ((lane >> 4) << 2);

  float4 xw0 = *(const float4*)(out + obase);        // xw for t=0
  float4 xw1 = *(const float4*)(out + obase + HH);   // xw for t=1
  float4 prev_hv = make_float4(0.f, 0.f, 0.f, 0.f);

  for (int t = 0; t < TT; ++t) {
    const u64* hq = hbuf + (unsigned)(t & 3) * 32768 + pload;
    u64* hn = hbuf + (unsigned)((t + 1) & 3) * 32768;
    unsigned tg = (unsigned)t;

    // ---- whole-batch tagged load + retry (1 RTT per round) ----
    u64 pk[32];
    for (;;) {
#pragma unroll
      for (int i = 0; i < 32; ++i)
        pk[i] = __hip_atomic_load(hq + (i >> 2) * 16 + (i & 3),
                                  __ATOMIC_RELAXED, __HIP_MEMORY_SCOPE_AGENT);
      unsigned bad = 0;
#pragma unroll
      for (int i = 0; i < 32; ++i) bad |= (unsigned)(pk[i] >> 32) ^ tg;
      if (__all((int)(bad == 0))) break;
    }

    // off-chain vmem issued now: ~1 full period old at the next drain
    if (t > 0) *(float4*)(out + obase + (size_t)(t - 1) * HH) = prev_hv;
    float4 xwf = make_float4(0.f, 0.f, 0.f, 0.f);
    if (t + 2 < TT) xwf = *(const float4*)(out + obase + (size_t)(t + 2) * HH);

    // ---- MFMA: 8 kt x (hi,lo) x 4 col-tiles, split-K/4 across waves ----
    f32x4 acc[4];
#pragma unroll
    for (int ct = 0; ct < 4; ++ct) acc[ct] = (f32x4)0.f;
#pragma unroll
    for (int kt = 0; kt < 8; ++kt) {
      union { unsigned u[4]; bf16x8 v; } pkk;
#pragma unroll
      for (int j = 0; j < 4; ++j) pkk.u[j] = (unsigned)pk[kt * 4 + j];
#pragma unroll
      for (int ct = 0; ct < 4; ++ct) {
        acc[ct] = __builtin_amdgcn_mfma_f32_16x16x32_bf16(pkk.v, whi[ct][kt],
                                                          acc[ct], 0, 0, 0);
        acc[ct] = __builtin_amdgcn_mfma_f32_16x16x32_bf16(pkk.v, wlo[ct][kt],
                                                          acc[ct], 0, 0, 0);
      }
    }

    // ---- split-K reduce across the 4 waves (lgkm-only barrier) ----
    int db = t & 1;
    int rr = (lane >> 4) << 2, cc = lane & 15;
#pragma unroll
    for (int ct = 0; ct < 4; ++ct)
#pragma unroll
      for (int i = 0; i < 4; ++i) red[db][w][rr + i][ct * 16 + cc] = acc[ct][i];
    asm volatile("s_waitcnt lgkmcnt(0)" ::: "memory");
    __builtin_amdgcn_s_barrier();
    asm volatile("" ::: "memory");

    int c4 = (tid & 15) << 2;
    float4 s = make_float4(0.f, 0.f, 0.f, 0.f);
#pragma unroll
    for (int ww = 0; ww < 4; ++ww) {
      float4 v = *(const float4*)&red[db][ww][erow_l][c4];
      s.x += v.x; s.y += v.y; s.z += v.z; s.w += v.w;
    }
    float4 hv;
    hv.x = ftanh(s.x + xw0.x);
    hv.y = ftanh(s.y + xw0.y);
    hv.z = ftanh(s.z + xw0.z);
    hv.w = ftanh(s.w + xw0.w);

    // ---- fire-and-forget tagged h publish (tag = t+1) ----
    if (t + 1 < TT) {
      u64 thi = ((u64)(unsigned)(t + 1)) << 32;
      unsigned lo0 = (unsigned)f2bf(hv.x) | ((unsigned)f2bf(hv.y) << 16);
      unsigned lo1 = (unsigned)f2bf(hv.z) | ((unsigned)f2bf(hv.w) << 16);
      __hip_atomic_store(hn + pstore, thi | lo0, __ATOMIC_RELAXED,
                         __HIP_MEMORY_SCOPE_AGENT);
      __hip_atomic_store(hn + pstore + 1, thi | lo1, __ATOMIC_RELAXED,
                         __HIP_MEMORY_SCOPE_AGENT);
    }
    prev_hv = hv;
    xw0 = xw1;
    xw1 = xwf;
  }
  *(float4*)(out + obase + (size_t)(TT - 1) * HH) = prev_hv;
}

// ------------------------------------------------------------- launch ------
extern "C" void kernel_launch(void* const* d_in, const int* in_sizes, int n_in,
                              void* d_out, int out_size, void* d_ws,
                              size_t ws_size, hipStream_t stream) {
  const float* x = (const float*)d_in[0];
  const float* h0 = (const float*)d_in[1];
  const float* Wx = (const float*)d_in[2];
  const float* Wh = (const float*)d_in[3];
  const float* b = (const float*)d_in[4];
  float* out = (float*)d_out;

  char* ws = (char*)d_ws;
  u64* hbuf = (u64*)(ws + 4096);                        // 1 MB (4 buffers)
  unsigned short* Wxh = (unsigned short*)(ws + 1052672);   // 2 MB
  unsigned short* Wxl = (unsigned short*)(ws + 3149824);   // 2 MB
  unsigned short* xbf = (unsigned short*)(ws + 5246976);   // 64 MB

  int fast = (ws_size >= 72355840ULL) ? 1 : 0;
  int nx = fast ? 16384 : 0;

  hipMemsetAsync(hbuf, 0, 1048576, stream);  // zero tags: no stale aliasing
  prep_kernel<<<nx + 1152, 256, 0, stream>>>(x, Wx, h0, Wxh, Wxl, hbuf, xbf,
                                             nx, fast);
  if (fast)
    xw_gemm_fast<<<dim3(8, 256), 256, 0, stream>>>(xbf, Wxh, Wxl, b, out);
  else
    xw_gemm_slow<<<dim3(8, 256), 256, 0, stream>>>(x, Wxh, Wxl, b, out);
  rnn_scan<<<64, 256, 0, stream>>>(Wh, out, hbuf);
}

// Round 9
// 2659.838 us; speedup vs baseline: 1.2022x; 1.2022x over previous
//
#include <hip/hip_runtime.h>

#define NB 64
#define TT 512
#define DD 1024
#define HH 1024

typedef unsigned long long u64;
typedef __attribute__((ext_vector_type(4))) float f32x4;
typedef __attribute__((ext_vector_type(8))) short bf16x8;

static __device__ __forceinline__ unsigned short f2bf(float f) {
  unsigned u = __float_as_uint(f);
  unsigned r = (u + 0x7fffu + ((u >> 16) & 1u)) >> 16;
  return (unsigned short)r;
}
static __device__ __forceinline__ float bf2f(unsigned short u) {
  return __uint_as_float(((unsigned)u) << 16);
}
// tanh(x) = 1 - 2/(e^{2x}+1), branch-free, saturating, ~1e-6 rel err
static __device__ __forceinline__ float ftanh(float x) {
  float z = __builtin_amdgcn_exp2f(x * 2.8853900817779268f);
  return 1.f - 2.f * __builtin_amdgcn_rcpf(z + 1.f);
}
static __device__ __forceinline__ void async_copy16(void* lds, const void* g) {
  __builtin_amdgcn_global_load_lds(
      (const __attribute__((address_space(1))) unsigned int*)g,
      (__attribute__((address_space(3))) unsigned int*)lds, 16, 0, 0);
}

// ---------------------------------------------------------------- prep -----
// blocks [0,nx): x fp32 -> xbf bf16, XOR-permuted global layout
// blocks [nx, nx+1024): transpose+split Wx -> Wxh/Wxl (permuted iff fast)
// blocks [nx+1024, nx+1056): h0 fp32 -> hbuf buffer 0 (bf16)
__global__ __launch_bounds__(256) void prep_kernel(
    const float* __restrict__ x, const float* __restrict__ Wx,
    const float* __restrict__ h0, unsigned short* __restrict__ Wxh,
    unsigned short* __restrict__ Wxl, unsigned short* __restrict__ hbuf0,
    unsigned short* __restrict__ xbf, int nx, int permuted) {
  __shared__ float tile[32][33];
  int b = blockIdx.x;
  int tid = threadIdx.x;
  if (b < nx) {
    int g = b * 256 + tid;        // 0..4194303
    int r = g >> 7, jb = g & 127; // row, 8-elem block within row
    int q = jb >> 3, j = jb & 7;
    const float4* src = (const float4*)(x + r * 1024 + jb * 8);
    float4 a0 = src[0], a1 = src[1];
    uint4 o;
    o.x = (unsigned)f2bf(a0.x) | ((unsigned)f2bf(a0.y) << 16);
    o.y = (unsigned)f2bf(a0.z) | ((unsigned)f2bf(a0.w) << 16);
    o.z = (unsigned)f2bf(a1.x) | ((unsigned)f2bf(a1.y) << 16);
    o.w = (unsigned)f2bf(a1.z) | ((unsigned)f2bf(a1.w) << 16);
    *(uint4*)((char*)xbf + (size_t)r * 2048 + q * 128 + ((j ^ (r & 7)) << 4)) = o;
  } else if (b < nx + 1024) {
    int bb = b - nx;
    int tk = (bb & 31) * 32;  // k tile origin
    int tn = (bb >> 5) * 32;  // n tile origin
    int tx = tid & 31;
    int ty = tid >> 5;  // 0..7
#pragma unroll
    for (int ii = 0; ii < 4; ++ii) {
      int kk = ty + ii * 8;
      tile[kk][tx] = Wx[(tk + kk) * HH + tn + tx];  // coalesced over tx
    }
    __syncthreads();
#pragma unroll
    for (int ii = 0; ii < 4; ++ii) {
      int a = ty + ii * 8;            // n offset in tile
      float wv = tile[tx][a];         // = Wx[tk+tx][tn+a]
      unsigned short hi = f2bf(wv);
      float lo = wv - bf2f(hi);
      int c = tn + a, k = tk + tx;
      int idx;
      if (permuted) {
        int qq = k >> 6, e = k & 63, j = e >> 3;
        idx = c * 1024 + qq * 64 + ((j ^ (c & 7)) << 3) + (e & 7);
      } else {
        idx = c * 1024 + k;
      }
      Wxh[idx] = hi;
      Wxl[idx] = f2bf(lo);
    }
  } else {
    int i = (b - nx - 1024) * 256 + tid;  // 0..8191
    int n = i >> 7, cb = i & 127;
    const float4* s4 = (const float4*)(h0 + n * 1024 + cb * 8);
    float4 a0 = s4[0], a1 = s4[1];
    uint4 o;
    o.x = (unsigned)f2bf(a0.x) | ((unsigned)f2bf(a0.y) << 16);
    o.y = (unsigned)f2bf(a0.z) | ((unsigned)f2bf(a0.w) << 16);
    o.z = (unsigned)f2bf(a1.x) | ((unsigned)f2bf(a1.y) << 16);
    o.w = (unsigned)f2bf(a1.z) | ((unsigned)f2bf(a1.w) << 16);
    *(uint4*)((char*)hbuf0 + (size_t)n * 2048 + cb * 16) = o;
  }
}

// -------------------------------------------------------- xw GEMM (fast) ---
// out = bf16(x)@(Wxh+Wxl) + b.  A/B pre-swizzled in global memory; staging
// is pure global_load_lds (16B), zero VALU. m97 2-barrier structure.
__global__ __launch_bounds__(256) void xw_gemm_fast(
    const unsigned short* __restrict__ xbf,
    const unsigned short* __restrict__ Wxh,
    const unsigned short* __restrict__ Wxl, const float* __restrict__ bias,
    float* __restrict__ out) {
  __shared__ unsigned short As[128 * 64];
  __shared__ unsigned short Bh[128 * 64];
  __shared__ unsigned short Bl[128 * 64];
  int tid = threadIdx.x;
  int w = tid >> 6, lane = tid & 63;
  int n0 = blockIdx.x * 128, row0 = blockIdx.y * 128;
  int wr = w >> 1, wc = w & 1;

  f32x4 acc[4][4];
#pragma unroll
  for (int m = 0; m < 4; ++m)
#pragma unroll
    for (int n = 0; n < 4; ++n) acc[m][n] = (f32x4)0.f;

  const char* xb = (const char*)xbf;
  const char* hb = (const char*)Wxh;
  const char* lb = (const char*)Wxl;

  for (int kc = 0; kc < 16; ++kc) {  // 16 chunks of K=64
    __syncthreads();  // previous MFMA done reading LDS
#pragma unroll
    for (int i = 0; i < 4; ++i) {
      int ub = i * 4096 + w * 1024;  // wave-uniform LDS byte base
      int off = ub + lane * 16;
      int r = off >> 7, inrow = off & 127;
      async_copy16((char*)As + ub,
                   xb + (size_t)(row0 + r) * 2048 + kc * 128 + inrow);
    }
#pragma unroll
    for (int i = 0; i < 4; ++i) {
      int ub = i * 4096 + w * 1024;
      int off = ub + lane * 16;
      int c = off >> 7, inrow = off & 127;
      async_copy16((char*)Bh + ub,
                   hb + (size_t)(n0 + c) * 2048 + kc * 128 + inrow);
      async_copy16((char*)Bl + ub,
                   lb + (size_t)(n0 + c) * 2048 + kc * 128 + inrow);
    }
    asm volatile("s_waitcnt vmcnt(0)" ::: "memory");
    __syncthreads();  // all staged
#pragma unroll
    for (int kt = 0; kt < 2; ++kt) {
      int krel2 = (kt * 32 + ((lane >> 4) << 3)) * 2;  // byte offset of k
      bf16x8 af[4], bhf[4], blf[4];
#pragma unroll
      for (int m = 0; m < 4; ++m) {
        int r = wr * 64 + m * 16 + (lane & 15);
        af[m] = *(const bf16x8*)((const char*)As + r * 128 +
                                 (krel2 ^ ((r & 7) << 4)));
      }
#pragma unroll
      for (int n = 0; n < 4; ++n) {
        int c = wc * 64 + n * 16 + (lane & 15);
        int off = c * 128 + (krel2 ^ ((c & 7) << 4));
        bhf[n] = *(const bf16x8*)((const char*)Bh + off);
        blf[n] = *(const bf16x8*)((const char*)Bl + off);
      }
#pragma unroll
      for (int m = 0; m < 4; ++m)
#pragma unroll
        for (int n = 0; n < 4; ++n) {
          acc[m][n] = __builtin_amdgcn_mfma_f32_16x16x32_bf16(af[m], bhf[n],
                                                              acc[m][n], 0, 0, 0);
          acc[m][n] = __builtin_amdgcn_mfma_f32_16x16x32_bf16(af[m], blf[n],
                                                              acc[m][n], 0, 0, 0);
        }
    }
  }

#pragma unroll
  for (int n = 0; n < 4; ++n) {
    int col = n0 + wc * 64 + n * 16 + (lane & 15);
    float bv = bias[col];
#pragma unroll
    for (int m = 0; m < 4; ++m) {
      int rbase = row0 + wr * 64 + m * 16 + ((lane >> 4) << 2);
#pragma unroll
      for (int i = 0; i < 4; ++i)
        out[(size_t)(rbase + i) * HH + col] = acc[m][n][i] + bv;
    }
  }
}

// -------------------------------------------------------- xw GEMM (slow) ---
// Fallback when ws too small for xbf: reg-staged with in-kernel convert.
__global__ __launch_bounds__(256) void xw_gemm_slow(
    const float* __restrict__ x, const unsigned short* __restrict__ Wxh,
    const unsigned short* __restrict__ Wxl, const float* __restrict__ bias,
    float* __restrict__ out) {
  __shared__ unsigned short As[128 * 64];
  __shared__ unsigned short Bh[128 * 64];
  __shared__ unsigned short Bl[128 * 64];

  int tid = threadIdx.x;
  int n0 = blockIdx.x * 128;
  int row0 = blockIdx.y * 128;
  int w = tid >> 6, lane = tid & 63;
  int wr = w >> 1, wc = w & 1;

  f32x4 acc[4][4];
#pragma unroll
  for (int m = 0; m < 4; ++m)
#pragma unroll
    for (int n = 0; n < 4; ++n) acc[m][n] = (f32x4)0.f;

  for (int kk = 0; kk < DD; kk += 64) {
    float4 av[8];
#pragma unroll
    for (int i = 0; i < 8; ++i) {
      int lin = tid + 256 * i;
      int r = lin >> 4, kq = lin & 15;
      av[i] = *(const float4*)(x + (size_t)(row0 + r) * DD + kk + kq * 4);
    }
    int4 bhv[4], blv[4];
#pragma unroll
    for (int i = 0; i < 4; ++i) {
      int lin = tid + 256 * i;
      int c = lin >> 3, kb = lin & 7;
      bhv[i] = *(const int4*)(Wxh + (size_t)(n0 + c) * DD + kk + kb * 8);
      blv[i] = *(const int4*)(Wxl + (size_t)(n0 + c) * DD + kk + kb * 8);
    }
    __syncthreads();
#pragma unroll
    for (int i = 0; i < 8; ++i) {
      int lin = tid + 256 * i;
      int r = lin >> 4, kq = lin & 15;
      uint2 u;
      u.x = (unsigned)f2bf(av[i].x) | ((unsigned)f2bf(av[i].y) << 16);
      u.y = (unsigned)f2bf(av[i].z) | ((unsigned)f2bf(av[i].w) << 16);
      *(uint2*)((char*)As + r * 128 + ((kq * 8) ^ ((r & 7) << 4))) = u;
    }
#pragma unroll
    for (int i = 0; i < 4; ++i) {
      int lin = tid + 256 * i;
      int c = lin >> 3, kb = lin & 7;
      int off = c * 128 + ((kb * 16) ^ ((c & 7) << 4));
      *(int4*)((char*)Bh + off) = bhv[i];
      *(int4*)((char*)Bl + off) = blv[i];
    }
    __syncthreads();
#pragma unroll
    for (int kt = 0; kt < 2; ++kt) {
      int krel2 = (kt * 32 + ((lane >> 4) << 3)) * 2;
      bf16x8 af[4], bhf[4], blf[4];
#pragma unroll
      for (int m = 0; m < 4; ++m) {
        int r = wr * 64 + m * 16 + (lane & 15);
        af[m] = *(const bf16x8*)((const char*)As + r * 128 +
                                 (krel2 ^ ((r & 7) << 4)));
      }
#pragma unroll
      for (int n = 0; n < 4; ++n) {
        int c = wc * 64 + n * 16 + (lane & 15);
        int off = c * 128 + (krel2 ^ ((c & 7) << 4));
        bhf[n] = *(const bf16x8*)((const char*)Bh + off);
        blf[n] = *(const bf16x8*)((const char*)Bl + off);
      }
#pragma unroll
      for (int m = 0; m < 4; ++m)
#pragma unroll
        for (int n = 0; n < 4; ++n) {
          acc[m][n] = __builtin_amdgcn_mfma_f32_16x16x32_bf16(af[m], bhf[n],
                                                              acc[m][n], 0, 0, 0);
          acc[m][n] = __builtin_amdgcn_mfma_f32_16x16x32_bf16(af[m], blf[n],
                                                              acc[m][n], 0, 0, 0);
        }
    }
    __syncthreads();
  }

#pragma unroll
  for (int n = 0; n < 4; ++n) {
    int col = n0 + wc * 64 + n * 16 + (lane & 15);
    float bv = bias[col];
#pragma unroll
    for (int m = 0; m < 4; ++m) {
      int rbase = row0 + wr * 64 + m * 16 + ((lane >> 4) << 2);
#pragma unroll
      for (int i = 0; i < 4; ++i)
        out[(size_t)(rbase + i) * HH + col] = acc[m][n][i] + bv;
    }
  }
}

// ---------------------------------------------------------------- scan -----
// r4 protocol (proven) + three deltas:
//  1) per-wave producer-subset poll: wave w polls only the 4 flags of the
//     WGs producing its K-chunk cols [w*256, w*256+256) (lanes 0-3).
//  2) lgkm-only reduce barrier (vmem stays in flight).
//  3) publish by LDS election: each wave h-store -> own vmcnt(0) -> lane0
//     atomicAdd on monotonic LDS counter; 4th incrementer of step t
//     (old==4t+3) stores the single WG flag. No second barrier.
// Safety: WG's h(t+1)-store follows the reduce barrier => all 4 waves
// passed poll(t) => collectively all 16 flags(t) => every WG finished
// reading h(t-1) => 2-buffer rotation race-free (skew <= 1).
__global__ __launch_bounds__(256) void rnn_scan(
    const float* __restrict__ Wh, float* __restrict__ out,
    unsigned short* __restrict__ hbuf, unsigned* __restrict__ flags) {
  int tid = threadIdx.x;
  int w = tid >> 6, lane = tid & 63;
  int p = blockIdx.x >> 4;  // batch group 0..3
  int q = blockIdx.x & 15;  // col group 0..15
  int n0 = p * 16;
  int c0 = q * 64;

  __shared__ float red[2][4][16][68];
  __shared__ unsigned cnt;
  if (tid == 0) cnt = 0u;

  // ---- Wh hi/lo fragments resident in registers, MFMA B-layout ----
  bf16x8 whi[4][8], wlo[4][8];
#pragma unroll
  for (int ct = 0; ct < 4; ++ct) {
#pragma unroll
    for (int kt = 0; kt < 8; ++kt) {
      int c = c0 + ct * 16 + (lane & 15);
      int kb = w * 256 + kt * 32 + ((lane >> 4) << 3);
#pragma unroll
      for (int j = 0; j < 8; ++j) {
        float wf = Wh[(size_t)(kb + j) * HH + c];
        unsigned short hi = f2bf(wf);
        whi[ct][kt][j] = (short)hi;
        wlo[ct][kt][j] = (short)f2bf(wf - bf2f(hi));
      }
    }
  }
  __syncthreads();  // cnt init visible

  int erow_l = tid >> 4;  // 0..15
  int erow = n0 + erow_l;
  int ecol = c0 + ((tid & 15) << 2);
  size_t obase = (size_t)erow * (TT * HH) + ecol;
  int hbase = erow * HH + ecol;
  int abase = (n0 + (lane & 15)) * HH + w * 256 + ((lane >> 4) << 3);

  unsigned* myflag = flags + p * 64 + q;
  // wave w's 4 producer WGs: q' = (w<<2)+0..3 (cols w*256..w*256+255)
  const unsigned* fp = flags + p * 64 + (w << 2);

  for (int t = 0; t < TT; ++t) {
    const unsigned short* hp = hbuf + (t & 1) * (NB * HH);
    unsigned short* hn = hbuf + ((t + 1) & 1) * (NB * HH);

    if (t > 0) {  // wait only for THIS wave's 4 producers
      unsigned tg = (unsigned)t;
      for (;;) {
        unsigned fv = 0xFFFFFFFFu;
        if (lane < 4)
          fv = __hip_atomic_load(fp + lane, __ATOMIC_RELAXED,
                                 __HIP_MEMORY_SCOPE_AGENT);
        if (__all((int)(fv >= tg))) break;
        __builtin_amdgcn_s_sleep(1);
      }
      asm volatile("" ::: "memory");
    }

    // xw(t): issued with the h-loads, arrives in parallel (LLC-resident)
    float4 xwc = *(const float4*)(out + obase + (size_t)t * HH);

    // ---- h loads (agent scope, coherent), batched ----
    const u64* hq = (const u64*)(hp + abase);
    u64 pu[8][2];
#pragma unroll
    for (int kt = 0; kt < 8; ++kt) {
      pu[kt][0] = __hip_atomic_load(hq + kt * 8, __ATOMIC_RELAXED,
                                    __HIP_MEMORY_SCOPE_AGENT);
      pu[kt][1] = __hip_atomic_load(hq + kt * 8 + 1, __ATOMIC_RELAXED,
                                    __HIP_MEMORY_SCOPE_AGENT);
    }

    f32x4 acc[4];
#pragma unroll
    for (int ct = 0; ct < 4; ++ct) acc[ct] = (f32x4)0.f;
#pragma unroll
    for (int kt = 0; kt < 8; ++kt) {
      union { u64 u[2]; bf16x8 v; } pk;
      pk.u[0] = pu[kt][0];
      pk.u[1] = pu[kt][1];
#pragma unroll
      for (int ct = 0; ct < 4; ++ct) {
        acc[ct] = __builtin_amdgcn_mfma_f32_16x16x32_bf16(pk.v, whi[ct][kt],
                                                          acc[ct], 0, 0, 0);
        acc[ct] = __builtin_amdgcn_mfma_f32_16x16x32_bf16(pk.v, wlo[ct][kt],
                                                          acc[ct], 0, 0, 0);
      }
    }

    // ---- split-K reduce across the 4 waves (lgkm-only barrier) ----
    int db = t & 1;
    int rr = (lane >> 4) << 2, cc = lane & 15;
#pragma unroll
    for (int ct = 0; ct < 4; ++ct)
#pragma unroll
      for (int i = 0; i < 4; ++i) red[db][w][rr + i][ct * 16 + cc] = acc[ct][i];
    asm volatile("s_waitcnt lgkmcnt(0)" ::: "memory");
    __builtin_amdgcn_s_barrier();
    asm volatile("" ::: "memory");

    int c4 = (tid & 15) << 2;
    float4 s = make_float4(0.f, 0.f, 0.f, 0.f);
#pragma unroll
    for (int ww = 0; ww < 4; ++ww) {
      float4 v = *(const float4*)&red[db][ww][erow_l][c4];
      s.x += v.x; s.y += v.y; s.z += v.z; s.w += v.w;
    }
    float4 hv;
    hv.x = ftanh(s.x + xwc.x);
    hv.y = ftanh(s.y + xwc.y);
    hv.z = ftanh(s.z + xwc.z);
    hv.w = ftanh(s.w + xwc.w);

    // out-store (normal, local-L2 ack; overlaps the h-store drain)
    *(float4*)(out + obase + (size_t)t * HH) = hv;

    if (t + 1 < TT) {
      // h for next step: 4 bf16 -> ONE 8B agent-scope store
      unsigned lo32 = (unsigned)f2bf(hv.x) | ((unsigned)f2bf(hv.y) << 16);
      unsigned hi32 = (unsigned)f2bf(hv.z) | ((unsigned)f2bf(hv.w) << 16);
      __hip_atomic_store((u64*)(hn + hbase), ((u64)hi32 << 32) | lo32,
                         __ATOMIC_RELAXED, __HIP_MEMORY_SCOPE_AGENT);
      // per-wave drain: h-store (and out-store) acked at coherence point
      asm volatile("s_waitcnt vmcnt(0)" ::: "memory");
      // election: 4th incrementer for step t publishes the WG flag
      if (lane == 0) {
        unsigned old = atomicAdd(&cnt, 1u);
        if (old == 4u * (unsigned)t + 3u)
          __hip_atomic_store(myflag, (unsigned)(t + 1), __ATOMIC_RELAXED,
                             __HIP_MEMORY_SCOPE_AGENT);
      }
    }
  }
}

// ------------------------------------------------------------- launch ------
extern "C" void kernel_launch(void* const* d_in, const int* in_sizes, int n_in,
                              void* d_out, int out_size, void* d_ws,
                              size_t ws_size, hipStream_t stream) {
  const float* x = (const float*)d_in[0];
  const float* h0 = (const float*)d_in[1];
  const float* Wx = (const float*)d_in[2];
  const float* Wh = (const float*)d_in[3];
  const float* b = (const float*)d_in[4];
  float* out = (float*)d_out;

  char* ws = (char*)d_ws;
  unsigned* flags = (unsigned*)ws;                            // 4 KB
  unsigned short* hbuf = (unsigned short*)(ws + 4096);        // 256 KB (2 bufs)
  unsigned short* Wxh = (unsigned short*)(ws + 266240);       // 2 MB
  unsigned short* Wxl = (unsigned short*)(ws + 2363392);      // 2 MB
  unsigned short* xbf = (unsigned short*)(ws + 4460544);      // 64 MB

  int fast = (ws_size >= 71569408ULL) ? 1 : 0;
  int nx = fast ? 16384 : 0;

  hipMemsetAsync(flags, 0, 4096, stream);
  prep_kernel<<<nx + 1056, 256, 0, stream>>>(x, Wx, h0, Wxh, Wxl, hbuf, xbf,
                                             nx, fast);
  if (fast)
    xw_gemm_fast<<<dim3(8, 256), 256, 0, stream>>>(xbf, Wxh, Wxl, b, out);
  else
    xw_gemm_slow<<<dim3(8, 256), 256, 0, stream>>>(x, Wxh, Wxl, b, out);
  rnn_scan<<<64, 256, 0, stream>>>(Wh, out, hbuf, flags);
}

// Round 10
// 1971.302 us; speedup vs baseline: 1.6222x; 1.3493x over previous
//
#include <hip/hip_runtime.h>

#define NB 64
#define TT 512
#define DD 1024
#define HH 1024

typedef unsigned long long u64;
typedef __attribute__((ext_vector_type(4))) float f32x4;
typedef __attribute__((ext_vector_type(8))) short bf16x8;

static __device__ __forceinline__ unsigned short f2bf(float f) {
  unsigned u = __float_as_uint(f);
  unsigned r = (u + 0x7fffu + ((u >> 16) & 1u)) >> 16;
  return (unsigned short)r;
}
static __device__ __forceinline__ float bf2f(unsigned short u) {
  return __uint_as_float(((unsigned)u) << 16);
}
// tanh(x) = 1 - 2/(e^{2x}+1); branch-free, saturating, ~1e-6 rel err
static __device__ __forceinline__ float ftanh(float x) {
  float z = __builtin_amdgcn_exp2f(x * 2.8853900817779268f);
  return 1.f - 2.f * __builtin_amdgcn_rcpf(z + 1.f);
}
// async global->LDS, 16B per lane; lds dest = wave-uniform base + lane*16
static __device__ __forceinline__ void async_copy16(void* lds, const void* g) {
  __builtin_amdgcn_global_load_lds(
      (const __attribute__((address_space(1))) unsigned int*)g,
      (__attribute__((address_space(3))) unsigned int*)lds, 16, 0, 0);
}

// ---------------------------------------------------------------- prep -----
// blocks [0,nx): x fp32 -> xbf bf16, XOR-permuted global layout:
//   element (r,k): q=k>>6, e=k&63, j=e>>3 -> byte r*2048 + q*128 +
//   ((j^(r&7))<<4) + (e&7)*2
// blocks [nx, nx+1024): transpose+split Wx -> Wxh/Wxl (permuted iff fast)
// blocks [nx+1024, nx+1056): h0 fp32 -> hbuf buffer 0 (bf16)
__global__ __launch_bounds__(256) void prep_kernel(
    const float* __restrict__ x, const float* __restrict__ Wx,
    const float* __restrict__ h0, unsigned short* __restrict__ Wxh,
    unsigned short* __restrict__ Wxl, unsigned short* __restrict__ hbuf0,
    unsigned short* __restrict__ xbf, int nx, int permuted) {
  __shared__ float tile[32][33];
  int b = blockIdx.x;
  int tid = threadIdx.x;
  if (b < nx) {
    int g = b * 256 + tid;        // 0..4194303
    int r = g >> 7, jb = g & 127; // row, 8-elem block within row
    int q = jb >> 3, j = jb & 7;
    const float4* src = (const float4*)(x + r * 1024 + jb * 8);
    float4 a0 = src[0], a1 = src[1];
    uint4 o;
    o.x = (unsigned)f2bf(a0.x) | ((unsigned)f2bf(a0.y) << 16);
    o.y = (unsigned)f2bf(a0.z) | ((unsigned)f2bf(a0.w) << 16);
    o.z = (unsigned)f2bf(a1.x) | ((unsigned)f2bf(a1.y) << 16);
    o.w = (unsigned)f2bf(a1.z) | ((unsigned)f2bf(a1.w) << 16);
    *(uint4*)((char*)xbf + (size_t)r * 2048 + q * 128 + ((j ^ (r & 7)) << 4)) = o;
  } else if (b < nx + 1024) {
    int bb = b - nx;
    int tk = (bb & 31) * 32;  // k tile origin
    int tn = (bb >> 5) * 32;  // n tile origin
    int tx = tid & 31;
    int ty = tid >> 5;  // 0..7
#pragma unroll
    for (int ii = 0; ii < 4; ++ii) {
      int kk = ty + ii * 8;
      tile[kk][tx] = Wx[(tk + kk) * HH + tn + tx];  // coalesced over tx
    }
    __syncthreads();
#pragma unroll
    for (int ii = 0; ii < 4; ++ii) {
      int a = ty + ii * 8;            // n offset in tile
      float wv = tile[tx][a];         // = Wx[tk+tx][tn+a]
      unsigned short hi = f2bf(wv);
      float lo = wv - bf2f(hi);
      int c = tn + a, k = tk + tx;
      int idx;
      if (permuted) {
        int qq = k >> 6, e = k & 63, j = e >> 3;
        idx = c * 1024 + qq * 64 + ((j ^ (c & 7)) << 3) + (e & 7);
      } else {
        idx = c * 1024 + k;
      }
      Wxh[idx] = hi;
      Wxl[idx] = f2bf(lo);
    }
  } else {
    int i = (b - nx - 1024) * 256 + tid;  // 0..8191
    int n = i >> 7, cb = i & 127;
    const float4* s4 = (const float4*)(h0 + n * 1024 + cb * 8);
    float4 a0 = s4[0], a1 = s4[1];
    uint4 o;
    o.x = (unsigned)f2bf(a0.x) | ((unsigned)f2bf(a0.y) << 16);
    o.y = (unsigned)f2bf(a0.z) | ((unsigned)f2bf(a0.w) << 16);
    o.z = (unsigned)f2bf(a1.x) | ((unsigned)f2bf(a1.y) << 16);
    o.w = (unsigned)f2bf(a1.z) | ((unsigned)f2bf(a1.w) << 16);
    *(uint4*)((char*)hbuf0 + (size_t)n * 2048 + cb * 16) = o;
  }
}

// -------------------------------------------------------- xw GEMM (fast) ---
// out = bf16(x)@(Wxh+Wxl) + b.  A/B pre-swizzled in global memory; staging
// is pure global_load_lds (16B), zero VALU. m97 2-barrier structure.
__global__ __launch_bounds__(256) void xw_gemm_fast(
    const unsigned short* __restrict__ xbf,
    const unsigned short* __restrict__ Wxh,
    const unsigned short* __restrict__ Wxl, const float* __restrict__ bias,
    float* __restrict__ out) {
  __shared__ unsigned short As[128 * 64];
  __shared__ unsigned short Bh[128 * 64];
  __shared__ unsigned short Bl[128 * 64];
  int tid = threadIdx.x;
  int w = tid >> 6, lane = tid & 63;
  int n0 = blockIdx.x * 128, row0 = blockIdx.y * 128;
  int wr = w >> 1, wc = w & 1;

  f32x4 acc[4][4];
#pragma unroll
  for (int m = 0; m < 4; ++m)
#pragma unroll
    for (int n = 0; n < 4; ++n) acc[m][n] = (f32x4)0.f;

  const char* xb = (const char*)xbf;
  const char* hb = (const char*)Wxh;
  const char* lb = (const char*)Wxl;

  for (int kc = 0; kc < 16; ++kc) {  // 16 chunks of K=64
    __syncthreads();  // previous MFMA done reading LDS
#pragma unroll
    for (int i = 0; i < 4; ++i) {
      int ub = i * 4096 + w * 1024;  // wave-uniform LDS byte base
      int off = ub + lane * 16;
      int r = off >> 7, inrow = off & 127;
      async_copy16((char*)As + ub,
                   xb + (size_t)(row0 + r) * 2048 + kc * 128 + inrow);
    }
#pragma unroll
    for (int i = 0; i < 4; ++i) {
      int ub = i * 4096 + w * 1024;
      int off = ub + lane * 16;
      int c = off >> 7, inrow = off & 127;
      async_copy16((char*)Bh + ub,
                   hb + (size_t)(n0 + c) * 2048 + kc * 128 + inrow);
      async_copy16((char*)Bl + ub,
                   lb + (size_t)(n0 + c) * 2048 + kc * 128 + inrow);
    }
    asm volatile("s_waitcnt vmcnt(0)" ::: "memory");
    __syncthreads();  // all staged
#pragma unroll
    for (int kt = 0; kt < 2; ++kt) {
      int krel2 = (kt * 32 + ((lane >> 4) << 3)) * 2;  // byte offset of k
      bf16x8 af[4], bhf[4], blf[4];
#pragma unroll
      for (int m = 0; m < 4; ++m) {
        int r = wr * 64 + m * 16 + (lane & 15);
        af[m] = *(const bf16x8*)((const char*)As + r * 128 +
                                 (krel2 ^ ((r & 7) << 4)));
      }
#pragma unroll
      for (int n = 0; n < 4; ++n) {
        int c = wc * 64 + n * 16 + (lane & 15);
        int off = c * 128 + (krel2 ^ ((c & 7) << 4));
        bhf[n] = *(const bf16x8*)((const char*)Bh + off);
        blf[n] = *(const bf16x8*)((const char*)Bl + off);
      }
#pragma unroll
      for (int m = 0; m < 4; ++m)
#pragma unroll
        for (int n = 0; n < 4; ++n) {
          acc[m][n] = __builtin_amdgcn_mfma_f32_16x16x32_bf16(af[m], bhf[n],
                                                              acc[m][n], 0, 0, 0);
          acc[m][n] = __builtin_amdgcn_mfma_f32_16x16x32_bf16(af[m], blf[n],
                                                              acc[m][n], 0, 0, 0);
        }
    }
  }

#pragma unroll
  for (int n = 0; n < 4; ++n) {
    int col = n0 + wc * 64 + n * 16 + (lane & 15);
    float bv = bias[col];
#pragma unroll
    for (int m = 0; m < 4; ++m) {
      int rbase = row0 + wr * 64 + m * 16 + ((lane >> 4) << 2);
#pragma unroll
      for (int i = 0; i < 4; ++i)
        out[(size_t)(rbase + i) * HH + col] = acc[m][n][i] + bv;
    }
  }
}

// -------------------------------------------------------- xw GEMM (slow) ---
// Fallback when ws too small for xbf: reg-staged with in-kernel convert.
__global__ __launch_bounds__(256) void xw_gemm_slow(
    const float* __restrict__ x, const unsigned short* __restrict__ Wxh,
    const unsigned short* __restrict__ Wxl, const float* __restrict__ bias,
    float* __restrict__ out) {
  __shared__ unsigned short As[128 * 64];
  __shared__ unsigned short Bh[128 * 64];
  __shared__ unsigned short Bl[128 * 64];

  int tid = threadIdx.x;
  int n0 = blockIdx.x * 128;
  int row0 = blockIdx.y * 128;
  int w = tid >> 6, lane = tid & 63;
  int wr = w >> 1, wc = w & 1;

  f32x4 acc[4][4];
#pragma unroll
  for (int m = 0; m < 4; ++m)
#pragma unroll
    for (int n = 0; n < 4; ++n) acc[m][n] = (f32x4)0.f;

  for (int kk = 0; kk < DD; kk += 64) {
    float4 av[8];
#pragma unroll
    for (int i = 0; i < 8; ++i) {
      int lin = tid + 256 * i;
      int r = lin >> 4, kq = lin & 15;
      av[i] = *(const float4*)(x + (size_t)(row0 + r) * DD + kk + kq * 4);
    }
    int4 bhv[4], blv[4];
#pragma unroll
    for (int i = 0; i < 4; ++i) {
      int lin = tid + 256 * i;
      int c = lin >> 3, kb = lin & 7;
      bhv[i] = *(const int4*)(Wxh + (size_t)(n0 + c) * DD + kk + kb * 8);
      blv[i] = *(const int4*)(Wxl + (size_t)(n0 + c) * DD + kk + kb * 8);
    }
    __syncthreads();
#pragma unroll
    for (int i = 0; i < 8; ++i) {
      int lin = tid + 256 * i;
      int r = lin >> 4, kq = lin & 15;
      uint2 u;
      u.x = (unsigned)f2bf(av[i].x) | ((unsigned)f2bf(av[i].y) << 16);
      u.y = (unsigned)f2bf(av[i].z) | ((unsigned)f2bf(av[i].w) << 16);
      *(uint2*)((char*)As + r * 128 + ((kq * 8) ^ ((r & 7) << 4))) = u;
    }
#pragma unroll
    for (int i = 0; i < 4; ++i) {
      int lin = tid + 256 * i;
      int c = lin >> 3, kb = lin & 7;
      int off = c * 128 + ((kb * 16) ^ ((c & 7) << 4));
      *(int4*)((char*)Bh + off) = bhv[i];
      *(int4*)((char*)Bl + off) = blv[i];
    }
    __syncthreads();
#pragma unroll
    for (int kt = 0; kt < 2; ++kt) {
      int krel2 = (kt * 32 + ((lane >> 4) << 3)) * 2;
      bf16x8 af[4], bhf[4], blf[4];
#pragma unroll
      for (int m = 0; m < 4; ++m) {
        int r = wr * 64 + m * 16 + (lane & 15);
        af[m] = *(const bf16x8*)((const char*)As + r * 128 +
                                 (krel2 ^ ((r & 7) << 4)));
      }
#pragma unroll
      for (int n = 0; n < 4; ++n) {
        int c = wc * 64 + n * 16 + (lane & 15);
        int off = c * 128 + (krel2 ^ ((c & 7) << 4));
        bhf[n] = *(const bf16x8*)((const char*)Bh + off);
        blf[n] = *(const bf16x8*)((const char*)Bl + off);
      }
#pragma unroll
      for (int m = 0; m < 4; ++m)
#pragma unroll
        for (int n = 0; n < 4; ++n) {
          acc[m][n] = __builtin_amdgcn_mfma_f32_16x16x32_bf16(af[m], bhf[n],
                                                              acc[m][n], 0, 0, 0);
          acc[m][n] = __builtin_amdgcn_mfma_f32_16x16x32_bf16(af[m], blf[n],
                                                              acc[m][n], 0, 0, 0);
        }
    }
    __syncthreads();
  }

#pragma unroll
  for (int n = 0; n < 4; ++n) {
    int col = n0 + wc * 64 + n * 16 + (lane & 15);
    float bv = bias[col];
#pragma unroll
    for (int m = 0; m < 4; ++m) {
      int rbase = row0 + wr * 64 + m * 16 + ((lane >> 4) << 2);
#pragma unroll
      for (int i = 0; i < 4; ++i)
        out[(size_t)(rbase + i) * HH + col] = acc[m][n][i] + bv;
    }
  }
}

// ---------------------------------------------------------------- scan -----
// EXACT champion r4 protocol (scan 1810us) with ONE surgical edit:
// barrier #1 (after split-K reduce write) is lgkm-only, so the t+2 xw
// prefetch (HBM, ~900cy) is never drained mid-step; it retires by
// barrier #2 (~2000cy later). All else byte-identical:
//   poll(t) lane<16 over the 16 WG flags (one cache line)
//   -> batched agent h-loads -> xw prefetch t+2 -> MFMA
//   -> reduce write -> [lgkm-only barrier] -> reduce read -> tanh
//   -> 8B agent h-store -> __syncthreads (vmcnt drain = h-store ack)
//   -> tid0 publishes WG flag -> deferred out-store(t-1).
__global__ __launch_bounds__(256) void rnn_scan(
    const float* __restrict__ Wh, float* __restrict__ out,
    unsigned short* __restrict__ hbuf, unsigned* __restrict__ flags) {
  int tid = threadIdx.x;
  int w = tid >> 6, lane = tid & 63;
  int p = blockIdx.x >> 4;  // batch group 0..3
  int q = blockIdx.x & 15;  // col group 0..15
  int n0 = p * 16;
  int c0 = q * 64;

  __shared__ float red[2][4][16][68];

  // ---- Wh hi/lo fragments resident in VGPRs, MFMA B-layout ----
  bf16x8 whi[4][8], wlo[4][8];
#pragma unroll
  for (int ct = 0; ct < 4; ++ct) {
#pragma unroll
    for (int kt = 0; kt < 8; ++kt) {
      int c = c0 + ct * 16 + (lane & 15);
      int kb = w * 256 + kt * 32 + ((lane >> 4) << 3);
#pragma unroll
      for (int j = 0; j < 8; ++j) {
        float wf = Wh[(size_t)(kb + j) * HH + c];
        unsigned short hi = f2bf(wf);
        whi[ct][kt][j] = (short)hi;
        wlo[ct][kt][j] = (short)f2bf(wf - bf2f(hi));
      }
    }
  }

  int erow_l = tid >> 4;  // 0..15
  int erow = n0 + erow_l;
  int ecol = c0 + ((tid & 15) << 2);
  size_t obase = (size_t)erow * (TT * HH) + ecol;
  int hbase = erow * HH + ecol;
  int abase = (n0 + (lane & 15)) * HH + w * 256 + ((lane >> 4) << 3);

  float4 xw0 = *(const float4*)(out + obase);        // xw for t=0
  float4 xw1 = *(const float4*)(out + obase + HH);   // xw for t=1
  float4 prev_hv = make_float4(0.f, 0.f, 0.f, 0.f);

  for (int t = 0; t < TT; ++t) {
    const unsigned short* hp = hbuf + (t & 1) * (NB * HH);
    unsigned short* hn = hbuf + ((t + 1) & 1) * (NB * HH);

    if (t > 0) {  // wait until all 16 WGs of group published step t
      unsigned tg = (unsigned)t;
      if (lane < 16) {
        const unsigned* fp2 = flags + p * 64 + lane;
        while (__hip_atomic_load(fp2, __ATOMIC_RELAXED,
                                 __HIP_MEMORY_SCOPE_AGENT) < tg)
          __builtin_amdgcn_s_sleep(1);
      }
      asm volatile("" ::: "memory");
    }

    // ---- h loads (agent scope, L2-bypass), batched ----
    const u64* hq = (const u64*)(hp + abase);
    u64 pu[8][2];
#pragma unroll
    for (int kt = 0; kt < 8; ++kt) {
      pu[kt][0] = __hip_atomic_load(hq + kt * 8, __ATOMIC_RELAXED,
                                    __HIP_MEMORY_SCOPE_AGENT);
      pu[kt][1] = __hip_atomic_load(hq + kt * 8 + 1, __ATOMIC_RELAXED,
                                    __HIP_MEMORY_SCOPE_AGENT);
    }

    // xw prefetch 2 steps ahead: issued AFTER the h-loads (vmcnt retires
    // in issue order, so waiting on h never waits on this); never drained
    // until barrier #2, by which point it is ~2000cy old.
    float4 xwf = make_float4(0.f, 0.f, 0.f, 0.f);
    if (t + 2 < TT) xwf = *(const float4*)(out + obase + (size_t)(t + 2) * HH);

    f32x4 acc[4];
#pragma unroll
    for (int ct = 0; ct < 4; ++ct) acc[ct] = (f32x4)0.f;
#pragma unroll
    for (int kt = 0; kt < 8; ++kt) {
      union { u64 u[2]; bf16x8 v; } pk;
      pk.u[0] = pu[kt][0];
      pk.u[1] = pu[kt][1];
#pragma unroll
      for (int ct = 0; ct < 4; ++ct) {
        acc[ct] = __builtin_amdgcn_mfma_f32_16x16x32_bf16(pk.v, whi[ct][kt],
                                                          acc[ct], 0, 0, 0);
        acc[ct] = __builtin_amdgcn_mfma_f32_16x16x32_bf16(pk.v, wlo[ct][kt],
                                                          acc[ct], 0, 0, 0);
      }
    }

    // ---- split-K reduce across the 4 waves ----
    int db = t & 1;
    int rr = (lane >> 4) << 2, cc = lane & 15;
#pragma unroll
    for (int ct = 0; ct < 4; ++ct)
#pragma unroll
      for (int i = 0; i < 4; ++i) red[db][w][rr + i][ct * 16 + cc] = acc[ct][i];
    // lgkm-only barrier: vmem (xw prefetch, deferred out-store) stays in
    // flight. LDS reads below are memory ops -> ordered by the clobbers.
    asm volatile("s_waitcnt lgkmcnt(0)" ::: "memory");
    __builtin_amdgcn_s_barrier();
    asm volatile("" ::: "memory");

    int c4 = (tid & 15) << 2;
    float4 s = make_float4(0.f, 0.f, 0.f, 0.f);
#pragma unroll
    for (int ww = 0; ww < 4; ++ww) {
      float4 v = *(const float4*)&red[db][ww][erow_l][c4];
      s.x += v.x; s.y += v.y; s.z += v.z; s.w += v.w;
    }
    float4 hv;
    hv.x = ftanh(s.x + xw0.x);
    hv.y = ftanh(s.y + xw0.y);
    hv.z = ftanh(s.z + xw0.z);
    hv.w = ftanh(s.w + xw0.w);

    // h for next step: 4 bf16 -> ONE 8B agent-scope store
    unsigned lo32 = (unsigned)f2bf(hv.x) | ((unsigned)f2bf(hv.y) << 16);
    unsigned hi32 = (unsigned)f2bf(hv.z) | ((unsigned)f2bf(hv.w) << 16);
    __hip_atomic_store((u64*)(hn + hbase), ((u64)hi32 << 32) | lo32,
                       __ATOMIC_RELAXED, __HIP_MEMORY_SCOPE_AGENT);

    __syncthreads();  // per-wave vmcnt(0) drain of h-store, then join
    if (tid == 0 && t + 1 < TT)
      __hip_atomic_store(flags + p * 64 + q, (unsigned)(t + 1),
                         __ATOMIC_RELAXED, __HIP_MEMORY_SCOPE_AGENT);

    // deferred out-store (off the serial chain; drained next step)
    if (t > 0) *(float4*)(out + obase + (size_t)(t - 1) * HH) = prev_hv;
    prev_hv = hv;
    xw0 = xw1;
    xw1 = xwf;
  }
  *(float4*)(out + obase + (size_t)(TT - 1) * HH) = prev_hv;
}

// ------------------------------------------------------------- launch ------
extern "C" void kernel_launch(void* const* d_in, const int* in_sizes, int n_in,
                              void* d_out, int out_size, void* d_ws,
                              size_t ws_size, hipStream_t stream) {
  const float* x = (const float*)d_in[0];
  const float* h0 = (const float*)d_in[1];
  const float* Wx = (const float*)d_in[2];
  const float* Wh = (const float*)d_in[3];
  const float* b = (const float*)d_in[4];
  float* out = (float*)d_out;

  char* ws = (char*)d_ws;
  unsigned* flags = (unsigned*)ws;                            // 4 KB
  unsigned short* hbuf = (unsigned short*)(ws + 4096);        // 256 KB (2 bufs)
  unsigned short* Wxh = (unsigned short*)(ws + 266240);       // 2 MB
  unsigned short* Wxl = (unsigned short*)(ws + 2363392);      // 2 MB
  unsigned short* xbf = (unsigned short*)(ws + 4460544);      // 64 MB

  int fast = (ws_size >= 71569408ULL) ? 1 : 0;
  int nx = fast ? 16384 : 0;

  hipMemsetAsync(flags, 0, 4096, stream);
  prep_kernel<<<nx + 1056, 256, 0, stream>>>(x, Wx, h0, Wxh, Wxl, hbuf, xbf,
                                             nx, fast);
  if (fast)
    xw_gemm_fast<<<dim3(8, 256), 256, 0, stream>>>(xbf, Wxh, Wxl, b, out);
  else
    xw_gemm_slow<<<dim3(8, 256), 256, 0, stream>>>(x, Wxh, Wxl, b, out);
  rnn_scan<<<64, 256, 0, stream>>>(Wh, out, hbuf, flags);
}

// Round 12
// 1940.510 us; speedup vs baseline: 1.6479x; 1.0159x over previous
//
#include <hip/hip_runtime.h>

#define NB 64
#define TT 512
#define DD 1024
#define HH 1024

typedef unsigned long long u64;
typedef __attribute__((ext_vector_type(4))) float f32x4;
typedef __attribute__((ext_vector_type(8))) short bf16x8;

static __device__ __forceinline__ unsigned short f2bf(float f) {
  unsigned u = __float_as_uint(f);
  unsigned r = (u + 0x7fffu + ((u >> 16) & 1u)) >> 16;
  return (unsigned short)r;
}
static __device__ __forceinline__ float bf2f(unsigned short u) {
  return __uint_as_float(((unsigned)u) << 16);
}
// tanh(x) = 1 - 2/(e^{2x}+1); branch-free, saturating, ~1e-6 rel err
static __device__ __forceinline__ float ftanh(float x) {
  float z = __builtin_amdgcn_exp2f(x * 2.8853900817779268f);
  return 1.f - 2.f * __builtin_amdgcn_rcpf(z + 1.f);
}
// async global->LDS, 16B per lane; lds dest = wave-uniform base + lane*16
static __device__ __forceinline__ void async_copy16(void* lds, const void* g) {
  __builtin_amdgcn_global_load_lds(
      (const __attribute__((address_space(1))) unsigned int*)g,
      (__attribute__((address_space(3))) unsigned int*)lds, 16, 0, 0);
}

// ---------------------------------------------------------------- prep -----
// blocks [0,nx): x fp32 -> xbf bf16, XOR-permuted global layout:
//   element (r,k): q=k>>6, e=k&63, j=e>>3 -> byte r*2048 + q*128 +
//   ((j^(r&7))<<4) + (e&7)*2
// blocks [nx, nx+1024): transpose+split Wx -> Wxh/Wxl (permuted iff fast)
// blocks [nx+1024, nx+1056): h0 fp32 -> hbuf buffer 0 (bf16)
__global__ __launch_bounds__(256) void prep_kernel(
    const float* __restrict__ x, const float* __restrict__ Wx,
    const float* __restrict__ h0, unsigned short* __restrict__ Wxh,
    unsigned short* __restrict__ Wxl, unsigned short* __restrict__ hbuf0,
    unsigned short* __restrict__ xbf, int nx, int permuted) {
  __shared__ float tile[32][33];
  int b = blockIdx.x;
  int tid = threadIdx.x;
  if (b < nx) {
    int g = b * 256 + tid;        // 0..4194303
    int r = g >> 7, jb = g & 127; // row, 8-elem block within row
    int q = jb >> 3, j = jb & 7;
    const float4* src = (const float4*)(x + r * 1024 + jb * 8);
    float4 a0 = src[0], a1 = src[1];
    uint4 o;
    o.x = (unsigned)f2bf(a0.x) | ((unsigned)f2bf(a0.y) << 16);
    o.y = (unsigned)f2bf(a0.z) | ((unsigned)f2bf(a0.w) << 16);
    o.z = (unsigned)f2bf(a1.x) | ((unsigned)f2bf(a1.y) << 16);
    o.w = (unsigned)f2bf(a1.z) | ((unsigned)f2bf(a1.w) << 16);
    *(uint4*)((char*)xbf + (size_t)r * 2048 + q * 128 + ((j ^ (r & 7)) << 4)) = o;
  } else if (b < nx + 1024) {
    int bb = b - nx;
    int tk = (bb & 31) * 32;  // k tile origin
    int tn = (bb >> 5) * 32;  // n tile origin
    int tx = tid & 31;
    int ty = tid >> 5;  // 0..7
#pragma unroll
    for (int ii = 0; ii < 4; ++ii) {
      int kk = ty + ii * 8;
      tile[kk][tx] = Wx[(tk + kk) * HH + tn + tx];  // coalesced over tx
    }
    __syncthreads();
#pragma unroll
    for (int ii = 0; ii < 4; ++ii) {
      int a = ty + ii * 8;            // n offset in tile
      float wv = tile[tx][a];         // = Wx[tk+tx][tn+a]
      unsigned short hi = f2bf(wv);
      float lo = wv - bf2f(hi);
      int c = tn + a, k = tk + tx;
      int idx;
      if (permuted) {
        int qq = k >> 6, e = k & 63, j = e >> 3;
        idx = c * 1024 + qq * 64 + ((j ^ (c & 7)) << 3) + (e & 7);
      } else {
        idx = c * 1024 + k;
      }
      Wxh[idx] = hi;
      Wxl[idx] = f2bf(lo);
    }
  } else {
    int i = (b - nx - 1024) * 256 + tid;  // 0..8191
    int n = i >> 7, cb = i & 127;
    const float4* s4 = (const float4*)(h0 + n * 1024 + cb * 8);
    float4 a0 = s4[0], a1 = s4[1];
    uint4 o;
    o.x = (unsigned)f2bf(a0.x) | ((unsigned)f2bf(a0.y) << 16);
    o.y = (unsigned)f2bf(a0.z) | ((unsigned)f2bf(a0.w) << 16);
    o.z = (unsigned)f2bf(a1.x) | ((unsigned)f2bf(a1.y) << 16);
    o.w = (unsigned)f2bf(a1.z) | ((unsigned)f2bf(a1.w) << 16);
    *(uint4*)((char*)hbuf0 + (size_t)n * 2048 + cb * 16) = o;
  }
}

// -------------------------------------------------------- xw GEMM (fast) ---
// out = bf16(x)@(Wxh+Wxl) + b.  A/B pre-swizzled in global memory; staging
// is pure global_load_lds (16B), zero VALU. m97 2-barrier structure.
__global__ __launch_bounds__(256) void xw_gemm_fast(
    const unsigned short* __restrict__ xbf,
    const unsigned short* __restrict__ Wxh,
    const unsigned short* __restrict__ Wxl, const float* __restrict__ bias,
    float* __restrict__ out) {
  __shared__ unsigned short As[128 * 64];
  __shared__ unsigned short Bh[128 * 64];
  __shared__ unsigned short Bl[128 * 64];
  int tid = threadIdx.x;
  int w = tid >> 6, lane = tid & 63;
  int n0 = blockIdx.x * 128, row0 = blockIdx.y * 128;
  int wr = w >> 1, wc = w & 1;

  f32x4 acc[4][4];
#pragma unroll
  for (int m = 0; m < 4; ++m)
#pragma unroll
    for (int n = 0; n < 4; ++n) acc[m][n] = (f32x4)0.f;

  const char* xb = (const char*)xbf;
  const char* hb = (const char*)Wxh;
  const char* lb = (const char*)Wxl;

  for (int kc = 0; kc < 16; ++kc) {  // 16 chunks of K=64
    __syncthreads();  // previous MFMA done reading LDS
#pragma unroll
    for (int i = 0; i < 4; ++i) {
      int ub = i * 4096 + w * 1024;  // wave-uniform LDS byte base
      int off = ub + lane * 16;
      int r = off >> 7, inrow = off & 127;
      async_copy16((char*)As + ub,
                   xb + (size_t)(row0 + r) * 2048 + kc * 128 + inrow);
    }
#pragma unroll
    for (int i = 0; i < 4; ++i) {
      int ub = i * 4096 + w * 1024;
      int off = ub + lane * 16;
      int c = off >> 7, inrow = off & 127;
      async_copy16((char*)Bh + ub,
                   hb + (size_t)(n0 + c) * 2048 + kc * 128 + inrow);
      async_copy16((char*)Bl + ub,
                   lb + (size_t)(n0 + c) * 2048 + kc * 128 + inrow);
    }
    asm volatile("s_waitcnt vmcnt(0)" ::: "memory");
    __syncthreads();  // all staged
#pragma unroll
    for (int kt = 0; kt < 2; ++kt) {
      int krel2 = (kt * 32 + ((lane >> 4) << 3)) * 2;  // byte offset of k
      bf16x8 af[4], bhf[4], blf[4];
#pragma unroll
      for (int m = 0; m < 4; ++m) {
        int r = wr * 64 + m * 16 + (lane & 15);
        af[m] = *(const bf16x8*)((const char*)As + r * 128 +
                                 (krel2 ^ ((r & 7) << 4)));
      }
#pragma unroll
      for (int n = 0; n < 4; ++n) {
        int c = wc * 64 + n * 16 + (lane & 15);
        int off = c * 128 + (krel2 ^ ((c & 7) << 4));
        bhf[n] = *(const bf16x8*)((const char*)Bh + off);
        blf[n] = *(const bf16x8*)((const char*)Bl + off);
      }
#pragma unroll
      for (int m = 0; m < 4; ++m)
#pragma unroll
        for (int n = 0; n < 4; ++n) {
          acc[m][n] = __builtin_amdgcn_mfma_f32_16x16x32_bf16(af[m], bhf[n],
                                                              acc[m][n], 0, 0, 0);
          acc[m][n] = __builtin_amdgcn_mfma_f32_16x16x32_bf16(af[m], blf[n],
                                                              acc[m][n], 0, 0, 0);
        }
    }
  }

#pragma unroll
  for (int n = 0; n < 4; ++n) {
    int col = n0 + wc * 64 + n * 16 + (lane & 15);
    float bv = bias[col];
#pragma unroll
    for (int m = 0; m < 4; ++m) {
      int rbase = row0 + wr * 64 + m * 16 + ((lane >> 4) << 2);
#pragma unroll
      for (int i = 0; i < 4; ++i)
        out[(size_t)(rbase + i) * HH + col] = acc[m][n][i] + bv;
    }
  }
}

// -------------------------------------------------------- xw GEMM (slow) ---
// Fallback when ws too small for xbf: reg-staged with in-kernel convert.
__global__ __launch_bounds__(256) void xw_gemm_slow(
    const float* __restrict__ x, const unsigned short* __restrict__ Wxh,
    const unsigned short* __restrict__ Wxl, const float* __restrict__ bias,
    float* __restrict__ out) {
  __shared__ unsigned short As[128 * 64];
  __shared__ unsigned short Bh[128 * 64];
  __shared__ unsigned short Bl[128 * 64];

  int tid = threadIdx.x;
  int n0 = blockIdx.x * 128;
  int row0 = blockIdx.y * 128;
  int w = tid >> 6, lane = tid & 63;
  int wr = w >> 1, wc = w & 1;

  f32x4 acc[4][4];
#pragma unroll
  for (int m = 0; m < 4; ++m)
#pragma unroll
    for (int n = 0; n < 4; ++n) acc[m][n] = (f32x4)0.f;

  for (int kk = 0; kk < DD; kk += 64) {
    float4 av[8];
#pragma unroll
    for (int i = 0; i < 8; ++i) {
      int lin = tid + 256 * i;
      int r = lin >> 4, kq = lin & 15;
      av[i] = *(const float4*)(x + (size_t)(row0 + r) * DD + kk + kq * 4);
    }
    int4 bhv[4], blv[4];
#pragma unroll
    for (int i = 0; i < 4; ++i) {
      int lin = tid + 256 * i;
      int c = lin >> 3, kb = lin & 7;
      bhv[i] = *(const int4*)(Wxh + (size_t)(n0 + c) * DD + kk + kb * 8);
      blv[i] = *(const int4*)(Wxl + (size_t)(n0 + c) * DD + kk + kb * 8);
    }
    __syncthreads();
#pragma unroll
    for (int i = 0; i < 8; ++i) {
      int lin = tid + 256 * i;
      int r = lin >> 4, kq = lin & 15;
      uint2 u;
      u.x = (unsigned)f2bf(av[i].x) | ((unsigned)f2bf(av[i].y) << 16);
      u.y = (unsigned)f2bf(av[i].z) | ((unsigned)f2bf(av[i].w) << 16);
      *(uint2*)((char*)As + r * 128 + ((kq * 8) ^ ((r & 7) << 4))) = u;
    }
#pragma unroll
    for (int i = 0; i < 4; ++i) {
      int lin = tid + 256 * i;
      int c = lin >> 3, kb = lin & 7;
      int off = c * 128 + ((kb * 16) ^ ((c & 7) << 4));
      *(int4*)((char*)Bh + off) = bhv[i];
      *(int4*)((char*)Bl + off) = blv[i];
    }
    __syncthreads();
#pragma unroll
    for (int kt = 0; kt < 2; ++kt) {
      int krel2 = (kt * 32 + ((lane >> 4) << 3)) * 2;
      bf16x8 af[4], bhf[4], blf[4];
#pragma unroll
      for (int m = 0; m < 4; ++m) {
        int r = wr * 64 + m * 16 + (lane & 15);
        af[m] = *(const bf16x8*)((const char*)As + r * 128 +
                                 (krel2 ^ ((r & 7) << 4)));
      }
#pragma unroll
      for (int n = 0; n < 4; ++n) {
        int c = wc * 64 + n * 16 + (lane & 15);
        int off = c * 128 + (krel2 ^ ((c & 7) << 4));
        bhf[n] = *(const bf16x8*)((const char*)Bh + off);
        blf[n] = *(const bf16x8*)((const char*)Bl + off);
      }
#pragma unroll
      for (int m = 0; m < 4; ++m)
#pragma unroll
        for (int n = 0; n < 4; ++n) {
          acc[m][n] = __builtin_amdgcn_mfma_f32_16x16x32_bf16(af[m], bhf[n],
                                                              acc[m][n], 0, 0, 0);
          acc[m][n] = __builtin_amdgcn_mfma_f32_16x16x32_bf16(af[m], blf[n],
                                                              acc[m][n], 0, 0, 0);
        }
    }
    __syncthreads();
  }

#pragma unroll
  for (int n = 0; n < 4; ++n) {
    int col = n0 + wc * 64 + n * 16 + (lane & 15);
    float bv = bias[col];
#pragma unroll
    for (int m = 0; m < 4; ++m) {
      int rbase = row0 + wr * 64 + m * 16 + ((lane >> 4) << 2);
#pragma unroll
      for (int i = 0; i < 4; ++i)
        out[(size_t)(rbase + i) * HH + col] = acc[m][n][i] + bv;
    }
  }
}

// ---------------------------------------------------------------- scan -----
// Champion r10 protocol, restored verbatim (r11's addressing deltas reverted
// after replay-race failure). Single micro-delta vs r10: pure-spin poll
// (no s_sleep between flag retries) — removes ~64cy detect quantization
// from the serial chain; semantics identical.
//   poll(t) lane<16 over the 16 WG flags (one cache line)
//   -> batched agent h-loads -> xw prefetch t+2 -> MFMA
//   -> reduce write -> [lgkm-only barrier] -> reduce read -> tanh
//   -> 8B agent h-store -> __syncthreads (vmcnt drain = h-store ack)
//   -> tid0 publishes WG flag -> deferred out-store(t-1).
__global__ __launch_bounds__(256) void rnn_scan(
    const float* __restrict__ Wh, float* __restrict__ out,
    unsigned short* __restrict__ hbuf, unsigned* __restrict__ flags) {
  int tid = threadIdx.x;
  int w = tid >> 6, lane = tid & 63;
  int p = blockIdx.x >> 4;  // batch group 0..3
  int q = blockIdx.x & 15;  // col group 0..15
  int n0 = p * 16;
  int c0 = q * 64;

  __shared__ float red[2][4][16][68];

  // ---- Wh hi/lo fragments resident in VGPRs, MFMA B-layout ----
  bf16x8 whi[4][8], wlo[4][8];
#pragma unroll
  for (int ct = 0; ct < 4; ++ct) {
#pragma unroll
    for (int kt = 0; kt < 8; ++kt) {
      int c = c0 + ct * 16 + (lane & 15);
      int kb = w * 256 + kt * 32 + ((lane >> 4) << 3);
#pragma unroll
      for (int j = 0; j < 8; ++j) {
        float wf = Wh[(size_t)(kb + j) * HH + c];
        unsigned short hi = f2bf(wf);
        whi[ct][kt][j] = (short)hi;
        wlo[ct][kt][j] = (short)f2bf(wf - bf2f(hi));
      }
    }
  }

  int erow_l = tid >> 4;  // 0..15
  int erow = n0 + erow_l;
  int ecol = c0 + ((tid & 15) << 2);
  size_t obase = (size_t)erow * (TT * HH) + ecol;
  int hbase = erow * HH + ecol;
  int abase = (n0 + (lane & 15)) * HH + w * 256 + ((lane >> 4) << 3);

  float4 xw0 = *(const float4*)(out + obase);        // xw for t=0
  float4 xw1 = *(const float4*)(out + obase + HH);   // xw for t=1
  float4 prev_hv = make_float4(0.f, 0.f, 0.f, 0.f);

  for (int t = 0; t < TT; ++t) {
    const unsigned short* hp = hbuf + (t & 1) * (NB * HH);
    unsigned short* hn = hbuf + ((t + 1) & 1) * (NB * HH);

    if (t > 0) {  // wait until all 16 WGs of group published step t
      unsigned tg = (unsigned)t;
      if (lane < 16) {
        const unsigned* fp2 = flags + p * 64 + lane;
        while (__hip_atomic_load(fp2, __ATOMIC_RELAXED,
                                 __HIP_MEMORY_SCOPE_AGENT) < tg) {
        }  // pure spin: retry period = load RTT, no sleep quantization
      }
      asm volatile("" ::: "memory");
    }

    // ---- h loads (agent scope, L2-bypass), batched ----
    const u64* hq = (const u64*)(hp + abase);
    u64 pu[8][2];
#pragma unroll
    for (int kt = 0; kt < 8; ++kt) {
      pu[kt][0] = __hip_atomic_load(hq + kt * 8, __ATOMIC_RELAXED,
                                    __HIP_MEMORY_SCOPE_AGENT);
      pu[kt][1] = __hip_atomic_load(hq + kt * 8 + 1, __ATOMIC_RELAXED,
                                    __HIP_MEMORY_SCOPE_AGENT);
    }

    // xw prefetch 2 steps ahead: issued AFTER the h-loads (vmcnt retires
    // in issue order, so waiting on h never waits on this); never drained
    // until barrier #2, by which point it is ~2000cy old.
    float4 xwf = make_float4(0.f, 0.f, 0.f, 0.f);
    if (t + 2 < TT) xwf = *(const float4*)(out + obase + (size_t)(t + 2) * HH);

    f32x4 acc[4];
#pragma unroll
    for (int ct = 0; ct < 4; ++ct) acc[ct] = (f32x4)0.f;
#pragma unroll
    for (int kt = 0; kt < 8; ++kt) {
      union { u64 u[2]; bf16x8 v; } pk;
      pk.u[0] = pu[kt][0];
      pk.u[1] = pu[kt][1];
#pragma unroll
      for (int ct = 0; ct < 4; ++ct) {
        acc[ct] = __builtin_amdgcn_mfma_f32_16x16x32_bf16(pk.v, whi[ct][kt],
                                                          acc[ct], 0, 0, 0);
        acc[ct] = __builtin_amdgcn_mfma_f32_16x16x32_bf16(pk.v, wlo[ct][kt],
                                                          acc[ct], 0, 0, 0);
      }
    }

    // ---- split-K reduce across the 4 waves ----
    int db = t & 1;
    int rr = (lane >> 4) << 2, cc = lane & 15;
#pragma unroll
    for (int ct = 0; ct < 4; ++ct)
#pragma unroll
      for (int i = 0; i < 4; ++i) red[db][w][rr + i][ct * 16 + cc] = acc[ct][i];
    // lgkm-only barrier: vmem (xw prefetch, deferred out-store) stays in
    // flight. LDS reads below are memory ops -> ordered by the clobbers.
    asm volatile("s_waitcnt lgkmcnt(0)" ::: "memory");
    __builtin_amdgcn_s_barrier();
    asm volatile("" ::: "memory");

    int c4 = (tid & 15) << 2;
    float4 s = make_float4(0.f, 0.f, 0.f, 0.f);
#pragma unroll
    for (int ww = 0; ww < 4; ++ww) {
      float4 v = *(const float4*)&red[db][ww][erow_l][c4];
      s.x += v.x; s.y += v.y; s.z += v.z; s.w += v.w;
    }
    float4 hv;
    hv.x = ftanh(s.x + xw0.x);
    hv.y = ftanh(s.y + xw0.y);
    hv.z = ftanh(s.z + xw0.z);
    hv.w = ftanh(s.w + xw0.w);

    // h for next step: 4 bf16 -> ONE 8B agent-scope store
    unsigned lo32 = (unsigned)f2bf(hv.x) | ((unsigned)f2bf(hv.y) << 16);
    unsigned hi32 = (unsigned)f2bf(hv.z) | ((unsigned)f2bf(hv.w) << 16);
    __hip_atomic_store((u64*)(hn + hbase), ((u64)hi32 << 32) | lo32,
                       __ATOMIC_RELAXED, __HIP_MEMORY_SCOPE_AGENT);

    __syncthreads();  // per-wave vmcnt(0) drain of h-store, then join
    if (tid == 0 && t + 1 < TT)
      __hip_atomic_store(flags + p * 64 + q, (unsigned)(t + 1),
                         __ATOMIC_RELAXED, __HIP_MEMORY_SCOPE_AGENT);

    // deferred out-store (off the serial chain; drained next step)
    if (t > 0) *(float4*)(out + obase + (size_t)(t - 1) * HH) = prev_hv;
    prev_hv = hv;
    xw0 = xw1;
    xw1 = xwf;
  }
  *(float4*)(out + obase + (size_t)(TT - 1) * HH) = prev_hv;
}

// ------------------------------------------------------------- launch ------
extern "C" void kernel_launch(void* const* d_in, const int* in_sizes, int n_in,
                              void* d_out, int out_size, void* d_ws,
                              size_t ws_size, hipStream_t stream) {
  const float* x = (const float*)d_in[0];
  const float* h0 = (const float*)d_in[1];
  const float* Wx = (const float*)d_in[2];
  const float* Wh = (const float*)d_in[3];
  const float* b = (const float*)d_in[4];
  float* out = (float*)d_out;

  char* ws = (char*)d_ws;
  unsigned* flags = (unsigned*)ws;                            // 4 KB
  unsigned short* hbuf = (unsigned short*)(ws + 4096);        // 256 KB (2 bufs)
  unsigned short* Wxh = (unsigned short*)(ws + 266240);       // 2 MB
  unsigned short* Wxl = (unsigned short*)(ws + 2363392);      // 2 MB
  unsigned short* xbf = (unsigned short*)(ws + 4460544);      // 64 MB

  int fast = (ws_size >= 71569408ULL) ? 1 : 0;
  int nx = fast ? 16384 : 0;

  hipMemsetAsync(flags, 0, 4096, stream);
  prep_kernel<<<nx + 1056, 256, 0, stream>>>(x, Wx, h0, Wxh, Wxl, hbuf, xbf,
                                             nx, fast);
  if (fast)
    xw_gemm_fast<<<dim3(8, 256), 256, 0, stream>>>(xbf, Wxh, Wxl, b, out);
  else
    xw_gemm_slow<<<dim3(8, 256), 256, 0, stream>>>(x, Wxh, Wxl, b, out);
  rnn_scan<<<64, 256, 0, stream>>>(Wh, out, hbuf, flags);
}